// Round 1
// baseline (1548.305 us; speedup 1.0000x reference)
//
#include <hip/hip_runtime.h>
#include <hip/hip_cooperative_groups.h>

namespace cg = cooperative_groups;

// GCN: 3x (GEMM 128x128 + normalized scatter-sum) + mean-pool + linear + softmax.
// R1: two-stage pool. R2: parallel scan. R3: bf16 + split-W MFMA GEMM.
// R4: agg multi-edge-in-flight; h pre-scaled by dinv. R5: CSR via two-level bucket sort.
// R6 FAILED (fusion cut gather parallelism). R7: 16 edges in flight; slab CSR.
// R8: 32 edges in flight; atomic/memset-free pool. R9: fp8 e4m3 gather payload.
// R10: single persistent cooperative kernel (10 grid.sync) — theory: ~130us of the
//      292us is inter-kernel boundary cost (launch + ramp/drain across 11 short
//      dispatches, none >44us in rocprof). Phase math identical to R9.
//      Fallback to the 11-kernel path if cooperative launch is refused.
// Assumes n <= 65536 (src packed u16), n <= 512*128, bucket load < CAP (8.5σ).

#define NF 128
#define MAXBUCK 512
#define CAP 2560           // slab capacity per bucket (mean 2176, sigma ~45)
#define PPG 8              // pool partials per graph
// fused-kernel scatter chunk (256 threads, 16/thread)
#define FCHUNK 4096
#define FPER 16
// legacy (fallback) scatter
#define L1_CHUNK 8192
#define L1_THREADS 512
#define L1_PER_THREAD 16

typedef __attribute__((ext_vector_type(8))) short short8;
typedef __attribute__((ext_vector_type(4))) float floatx4;
typedef __attribute__((ext_vector_type(2))) float floatx2;

__device__ __forceinline__ unsigned int bf16_rne(float x) {
    unsigned int u = __float_as_uint(x);
    return (u + 0x7fffu + ((u >> 16) & 1u)) >> 16;
}
__device__ __forceinline__ unsigned int pack_bf16_rne(float x, float y) {
    return bf16_rne(x) | (bf16_rne(y) << 16);
}
__device__ __forceinline__ float bf16_to_f32(unsigned short h) {
    return __uint_as_float((unsigned int)h << 16);
}

// ---------------- fused cooperative kernel ----------------

struct KP {
    const float* x;
    const int* row; const int* colv; const int* batch;
    const float* W0; const float* b0; const float* W1; const float* b1;
    const float* W2; const float* b2; const float* linW; const float* linb;
    int* bucket_cursor; unsigned int* buck_arr; unsigned short* src16;
    int* starts; int* ends; float* dinv;
    unsigned char* gbuf8; unsigned short* abuf; float* pooled_part;
    unsigned short* whi; unsigned short* wlo;
    float* out;
    int n, ne, etot, nbuck, n_graphs;
};

union alignas(16) SMemU {
    struct {                                  // scatter: 28 KB
        unsigned int hist[MAXBUCK], lbase[MAXBUCK], lcur[MAXBUCK], runb[MAXBUCK];
        unsigned int sa[MAXBUCK], sb[MAXBUCK];
        unsigned int reorder[FCHUNK];
    } sc;
    struct {                                  // fine: ~7 KB
        unsigned int cnt[128]; unsigned int lsc[256]; unsigned int lc[128];
        unsigned short srcbuf[CAP];
    } fi;
    unsigned short As[64 * 136];              // gemm: 17 KB
    float ph[64 * NF];                        // head: 32 KB  -> union = 32 KB
};

__device__ __forceinline__ void ph_repack(const KP& p) {
    int b = blockIdx.x;
    if (b == 24) {
        for (int i = threadIdx.x; i <= MAXBUCK; i += 256) p.bucket_cursor[i] = 0;
        return;
    }
    if (b >= 24) return;
    int wsel = b >> 3;
    const float* W = (wsel == 0) ? p.W0 : (wsel == 1) ? p.W1 : p.W2;
    int idx = (b & 7) * 256 + threadIdx.x;    // 0..2047
    int slab = wsel * NF * NF;
    int l = idx & 63;
    int t = (idx >> 6) & 7;
    int s = idx >> 9;
    int kbase = s * 32 + (l >> 4) * 8;
    int nn = t * 16 + (l & 15);
    #pragma unroll
    for (int j = 0; j < 8; ++j) {
        float w = W[(kbase + j) * NF + nn];
        unsigned int h = bf16_rne(w);
        float hf = __uint_as_float(h << 16);
        unsigned int lo = bf16_rne(w - hf);
        p.whi[slab + idx * 8 + j] = (unsigned short)h;
        p.wlo[slab + idx * 8 + j] = (unsigned short)lo;
    }
}

__device__ void ph_scatter(const KP& p, SMemU& sm) {
    int t = threadIdx.x;
    int nchunk = (p.etot + FCHUNK - 1) / FCHUNK;
    for (int ch = blockIdx.x; ch < nchunk; ch += gridDim.x) {
        int e0 = ch * FCHUNK;
        int cnt_here = min(p.etot - e0, FCHUNK);
        sm.sc.hist[t] = 0u; sm.sc.hist[t + 256] = 0u;
        __syncthreads();
        unsigned int myv[FPER];
        #pragma unroll
        for (int j = 0; j < FPER; ++j) {
            int e = e0 + j * 256 + t;
            if (e < p.etot) {
                int s, d;
                if (e < p.ne) { s = p.row[e]; d = p.colv[e]; } else { s = d = e - p.ne; }
                myv[j] = (unsigned int)s | ((unsigned int)d << 16);
                atomicAdd(&sm.sc.hist[d >> 7], 1u);
            } else myv[j] = 0xffffffffu;
        }
        __syncthreads();
        sm.sc.sa[t] = sm.sc.hist[t]; sm.sc.sa[t + 256] = sm.sc.hist[t + 256];
        __syncthreads();
        unsigned int* pin = sm.sc.sa; unsigned int* pout = sm.sc.sb;
        for (int off = 1; off < MAXBUCK; off <<= 1) {
            pout[t] = pin[t] + ((t >= off) ? pin[t - off] : 0u);
            int u = t + 256;                    // u >= 256 >= off always
            pout[u] = pin[u] + pin[u - off];
            __syncthreads();
            unsigned int* tmp = pin; pin = pout; pout = tmp;
        }
        for (int i = t; i < MAXBUCK; i += 256) {
            unsigned int ex = pin[i] - sm.sc.hist[i];
            sm.sc.lbase[i] = ex; sm.sc.lcur[i] = ex;
            if (i < p.nbuck && sm.sc.hist[i] > 0u)
                sm.sc.runb[i] = (unsigned int)atomicAdd(&p.bucket_cursor[i], (int)sm.sc.hist[i]);
        }
        __syncthreads();
        #pragma unroll
        for (int j = 0; j < FPER; ++j) {
            unsigned int v = myv[j];
            if (v != 0xffffffffu) {
                unsigned int pp = atomicAdd(&sm.sc.lcur[v >> 23], 1u);
                sm.sc.reorder[pp] = v;
            }
        }
        __syncthreads();
        for (int i = t; i < cnt_here; i += 256) {
            unsigned int v = sm.sc.reorder[i];
            unsigned int b = v >> 23;
            p.buck_arr[(size_t)b * CAP + sm.sc.runb[b] + ((unsigned int)i - sm.sc.lbase[b])] = v;
        }
        __syncthreads();
    }
}

__device__ void ph_fine(const KP& p, SMemU& sm) {
    int t = threadIdx.x;
    for (int b = blockIdx.x; b < p.nbuck; b += gridDim.x) {
        int base = b * CAP;
        int m = min(p.bucket_cursor[b], CAP);
        int node0 = b << 7;
        int nn = min(128, p.n - node0);
        if (t < 128) sm.fi.cnt[t] = 0u;
        __syncthreads();
        for (int i = t; i < m; i += 256)
            atomicAdd(&sm.fi.cnt[(p.buck_arr[base + i] >> 16) - node0], 1u);
        __syncthreads();
        unsigned int v0 = (t < 128) ? sm.fi.cnt[t] : 0u;
        sm.fi.lsc[t] = v0;
        __syncthreads();
        #pragma unroll
        for (int off = 1; off < 128; off <<= 1) {
            unsigned int add = (t >= off) ? sm.fi.lsc[t - off] : 0u;
            __syncthreads();
            sm.fi.lsc[t] += add;
            __syncthreads();
        }
        if (t < 128) {
            unsigned int ex = sm.fi.lsc[t] - v0;
            sm.fi.lc[t] = ex;
            if (t < nn) {
                p.starts[node0 + t] = base + (int)ex;
                p.ends[node0 + t]   = base + (int)(ex + v0);
                p.dinv[node0 + t]   = rsqrtf((float)v0);   // deg >= 1 (self-loop)
            }
        }
        __syncthreads();
        for (int i = t; i < m; i += 256) {
            unsigned int v = p.buck_arr[base + i];
            unsigned int pp = atomicAdd(&sm.fi.lc[(v >> 16) - node0], 1u);
            sm.fi.srcbuf[pp] = (unsigned short)(v & 0xffffu);
        }
        __syncthreads();
        for (int i = t; i < m; i += 256)
            p.src16[base + i] = sm.fi.srcbuf[i];
        __syncthreads();
    }
}

__device__ void ph_gemm(SMemU& sm, const float* Af, const unsigned short* Ab,
                        const unsigned short* Whi, const unsigned short* Wlo,
                        const float* dinv, unsigned char* Out, int M) {
    int tid = threadIdx.x;
    int ntile = (M + 63) >> 6;
    for (int tile = blockIdx.x; tile < ntile; tile += gridDim.x) {
        int row0 = tile * 64;
        if (Af) {
            for (int c = tid; c < 1024; c += 256) {
                int r = c >> 4, off = c & 15;
                int gr = min(row0 + r, M - 1);
                const float4* pf = (const float4*)(Af + (size_t)gr * NF) + off * 2;
                float4 v0 = pf[0], v1 = pf[1];
                uint4 pk;
                pk.x = pack_bf16_rne(v0.x, v0.y);
                pk.y = pack_bf16_rne(v0.z, v0.w);
                pk.z = pack_bf16_rne(v1.x, v1.y);
                pk.w = pack_bf16_rne(v1.z, v1.w);
                *(uint4*)(&sm.As[r * 136 + off * 8]) = pk;
            }
        } else {
            for (int c = tid; c < 1024; c += 256) {
                int r = c >> 4, off = c & 15;
                int gr = min(row0 + r, M - 1);
                *(uint4*)(&sm.As[r * 136 + off * 8]) = ((const uint4*)(Ab + (size_t)gr * NF))[off];
            }
        }
        __syncthreads();

        int wave = tid >> 6, l = tid & 63;
        int q = l >> 4, c16 = l & 15;
        int wrow0 = wave * 16;

        floatx4 acc[8];
        #pragma unroll
        for (int t = 0; t < 8; ++t) acc[t] = (floatx4){0.f, 0.f, 0.f, 0.f};

        #pragma unroll
        for (int s = 0; s < 4; ++s) {
            short8 a = *(const short8*)(&sm.As[(wrow0 + c16) * 136 + s * 32 + q * 8]);
            #pragma unroll
            for (int t = 0; t < 8; ++t) {
                short8 bh = *(const short8*)(Whi + ((size_t)((s * 8 + t) * 64 + l) * 8));
                acc[t] = __builtin_amdgcn_mfma_f32_16x16x32_bf16(a, bh, acc[t], 0, 0, 0);
                short8 bl = *(const short8*)(Wlo + ((size_t)((s * 8 + t) * 64 + l) * 8));
                acc[t] = __builtin_amdgcn_mfma_f32_16x16x32_bf16(a, bl, acc[t], 0, 0, 0);
            }
        }

        float ds[4];
        #pragma unroll
        for (int i = 0; i < 4; ++i) {
            int gr = row0 + wrow0 + q * 4 + i;
            ds[i] = (gr < M) ? dinv[gr] : 0.f;
        }
        #pragma unroll
        for (int t = 0; t < 8; ++t) {
            #pragma unroll
            for (int i = 0; i < 4; ++i) {
                int gr = row0 + wrow0 + q * 4 + i;
                if (gr < M) {
                    float v = acc[t][i] * ds[i];
                    unsigned int pk = __builtin_amdgcn_cvt_pk_fp8_f32(v, v, 0, false);
                    Out[(size_t)gr * NF + t * 16 + c16] = (unsigned char)(pk & 0xffu);
                }
            }
        }
        __syncthreads();
    }
}

__device__ void ph_agg(const KP& p, const unsigned char* hs8, const float* bias,
                       unsigned short* out, int do_relu) {
    int wave = threadIdx.x >> 6;
    int lane = threadIdx.x & 63;
    int g = lane >> 4;
    int f = lane & 15;
    int ngrp = (p.n + 3) >> 2;
    const uint2* h2 = (const uint2*)hs8;
    for (int grp = blockIdx.x; grp < ngrp; grp += gridDim.x) {
        int node = grp * 4 + wave;
        if (node >= p.n) continue;
        int start = p.starts[node], end = p.ends[node];

        float acc[8];
        #pragma unroll
        for (int j = 0; j < 8; ++j) acc[j] = 0.f;

        for (int base = start; base < end; base += 32) {
            int   sidx[8];
            float msk[8];
            #pragma unroll
            for (int j = 0; j < 8; ++j) {
                int e = base + g + 4 * j;
                bool v = e < end;
                sidx[j] = (int)p.src16[v ? e : start];
                msk[j]  = v ? 1.f : 0.f;
            }
            uint2 rr[8];
            #pragma unroll
            for (int j = 0; j < 8; ++j)
                rr[j] = h2[(size_t)sidx[j] * 16 + f];
            #pragma unroll
            for (int j = 0; j < 8; ++j) {
                float m = msk[j];
                floatx2 p0 = __builtin_amdgcn_cvt_pk_f32_fp8(rr[j].x, false);
                floatx2 p1 = __builtin_amdgcn_cvt_pk_f32_fp8(rr[j].x, true);
                floatx2 p2 = __builtin_amdgcn_cvt_pk_f32_fp8(rr[j].y, false);
                floatx2 p3 = __builtin_amdgcn_cvt_pk_f32_fp8(rr[j].y, true);
                acc[0] = fmaf(m, p0.x, acc[0]);
                acc[1] = fmaf(m, p0.y, acc[1]);
                acc[2] = fmaf(m, p1.x, acc[2]);
                acc[3] = fmaf(m, p1.y, acc[3]);
                acc[4] = fmaf(m, p2.x, acc[4]);
                acc[5] = fmaf(m, p2.y, acc[5]);
                acc[6] = fmaf(m, p3.x, acc[6]);
                acc[7] = fmaf(m, p3.y, acc[7]);
            }
        }

        #pragma unroll
        for (int j = 0; j < 8; ++j) {
            acc[j] += __shfl_xor(acc[j], 16);
            acc[j] += __shfl_xor(acc[j], 32);
        }

        if (g == 0) {
            float dd = p.dinv[node];
            float4 b0 = ((const float4*)bias)[2 * f];
            float4 b1 = ((const float4*)bias)[2 * f + 1];
            float r[8];
            r[0] = fmaf(dd, acc[0], b0.x); r[1] = fmaf(dd, acc[1], b0.y);
            r[2] = fmaf(dd, acc[2], b0.z); r[3] = fmaf(dd, acc[3], b0.w);
            r[4] = fmaf(dd, acc[4], b1.x); r[5] = fmaf(dd, acc[5], b1.y);
            r[6] = fmaf(dd, acc[6], b1.z); r[7] = fmaf(dd, acc[7], b1.w);
            if (do_relu) {
                #pragma unroll
                for (int j = 0; j < 8; ++j) r[j] = fmaxf(r[j], 0.f);
            }
            uint4 pk;
            pk.x = pack_bf16_rne(r[0], r[1]);
            pk.y = pack_bf16_rne(r[2], r[3]);
            pk.z = pack_bf16_rne(r[4], r[5]);
            pk.w = pack_bf16_rne(r[6], r[7]);
            ((uint4*)out)[(size_t)node * 16 + f] = pk;
        }
    }
}

__device__ void ph_pool(const KP& p) {
    int t = threadIdx.x;
    int half = t >> 7, tt = t & 127;
    int nslab = p.n_graphs * PPG;
    for (int s2 = blockIdx.x; s2 * 2 < nslab; s2 += gridDim.x) {
        int b = s2 * 2 + half;
        if (b >= nslab) continue;
        int g = b / PPG;
        int j = b % PPG;
        int lo = 0, hi = p.n;
        while (lo < hi) { int mid = (lo + hi) >> 1; if (p.batch[mid] < g) lo = mid + 1; else hi = mid; }
        int s = lo;
        lo = s; hi = p.n;
        while (lo < hi) { int mid = (lo + hi) >> 1; if (p.batch[mid] < g + 1) lo = mid + 1; else hi = mid; }
        int e = lo;
        int len = e - s;
        int chunk = (len + PPG - 1) / PPG;
        int i0 = s + j * chunk;
        int i1 = min(e, i0 + chunk);
        float acc = 0.f;
        for (int i = i0; i < i1; ++i)
            acc += bf16_to_f32(p.abuf[(size_t)i * NF + tt]);
        p.pooled_part[(size_t)b * NF + tt] = acc;
    }
}

__device__ void ph_head(const KP& p, SMemU& sm) {
    if (blockIdx.x != 0) return;
    int t = threadIdx.x;
    for (int i = t; i < p.n_graphs * NF; i += 256) {
        int g = i >> 7, f = i & 127;
        float s = 0.f;
        #pragma unroll
        for (int j = 0; j < PPG; ++j)
            s += p.pooled_part[(size_t)(g * PPG + j) * NF + f];
        sm.ph[i] = s;
    }
    __syncthreads();
    for (int pp = t; pp < p.n_graphs * 16; pp += 256) {
        int g = pp >> 4, c = pp & 15;
        int lo = 0, hi = p.n;
        while (lo < hi) { int mid = (lo + hi) >> 1; if (p.batch[mid] < g) lo = mid + 1; else hi = mid; }
        int start = lo;
        lo = start; hi = p.n;
        while (lo < hi) { int mid = (lo + hi) >> 1; if (p.batch[mid] < g + 1) lo = mid + 1; else hi = mid; }
        float inv_cnt = 1.f / fmaxf((float)(lo - start), 1.f);
        float acc = p.linb[c];
        for (int k = 0; k < NF; ++k)
            acc += sm.ph[g * NF + k] * inv_cnt * p.linW[k * 16 + c];
        float m = acc;
        #pragma unroll
        for (int s2 = 8; s2 >= 1; s2 >>= 1) m = fmaxf(m, __shfl_xor(m, s2, 16));
        float e = expf(acc - m);
        float ssum = e;
        #pragma unroll
        for (int s2 = 8; s2 >= 1; s2 >>= 1) ssum += __shfl_xor(ssum, s2, 16);
        p.out[pp] = e / ssum;
    }
}

__global__ __launch_bounds__(256, 4) void k_all(KP p) {
    cg::grid_group grid = cg::this_grid();
    __shared__ SMemU sm;
    const size_t WSLAB = (size_t)NF * NF;

    ph_repack(p);
    __threadfence(); grid.sync();
    ph_scatter(p, sm);
    __threadfence(); grid.sync();
    ph_fine(p, sm);
    __threadfence(); grid.sync();
    ph_gemm(sm, p.x, nullptr, p.whi, p.wlo, p.dinv, p.gbuf8, p.n);
    __threadfence(); grid.sync();
    ph_agg(p, p.gbuf8, p.b0, p.abuf, 1);
    __threadfence(); grid.sync();
    ph_gemm(sm, nullptr, p.abuf, p.whi + WSLAB, p.wlo + WSLAB, p.dinv, p.gbuf8, p.n);
    __threadfence(); grid.sync();
    ph_agg(p, p.gbuf8, p.b1, p.abuf, 1);
    __threadfence(); grid.sync();
    ph_gemm(sm, nullptr, p.abuf, p.whi + 2 * WSLAB, p.wlo + 2 * WSLAB, p.dinv, p.gbuf8, p.n);
    __threadfence(); grid.sync();
    ph_agg(p, p.gbuf8, p.b2, p.abuf, 0);
    __threadfence(); grid.sync();
    ph_pool(p);
    __threadfence(); grid.sync();
    ph_head(p, sm);
}

// ---------------- legacy kernels (fallback path, verbatim R9) ----------------

__global__ __launch_bounds__(256) void k_repack_w3(const float* __restrict__ W0,
                                                   const float* __restrict__ W1,
                                                   const float* __restrict__ W2,
                                                   unsigned short* __restrict__ whi,
                                                   unsigned short* __restrict__ wlo,
                                                   int* __restrict__ bucket_cursor) {
    if (blockIdx.x == 0) {
        for (int i = threadIdx.x; i <= MAXBUCK; i += 256) bucket_cursor[i] = 0;
    }
    int wsel = blockIdx.x >> 3;
    const float* W = (wsel == 0) ? W0 : (wsel == 1) ? W1 : W2;
    int idx = (blockIdx.x & 7) * 256 + threadIdx.x;
    int slab = wsel * NF * NF;
    int l = idx & 63;
    int t = (idx >> 6) & 7;
    int s = idx >> 9;
    int kbase = s * 32 + (l >> 4) * 8;
    int nn = t * 16 + (l & 15);
    #pragma unroll
    for (int j = 0; j < 8; ++j) {
        float w = W[(kbase + j) * NF + nn];
        unsigned int h = bf16_rne(w);
        float hf = __uint_as_float(h << 16);
        unsigned int lo = bf16_rne(w - hf);
        whi[slab + idx * 8 + j] = (unsigned short)h;
        wlo[slab + idx * 8 + j] = (unsigned short)lo;
    }
}

__global__ __launch_bounds__(L1_THREADS) void k_bucket_scatter(
        const int* __restrict__ row, const int* __restrict__ colv,
        int* __restrict__ bucket_cursor, unsigned int* __restrict__ buck_arr,
        int ne, int etot, int nbuck) {
    __shared__ unsigned int hist[MAXBUCK];
    __shared__ unsigned int lbase[MAXBUCK];
    __shared__ unsigned int lcur[MAXBUCK];
    __shared__ unsigned int runb[MAXBUCK];
    __shared__ unsigned int sa[MAXBUCK], sb[MAXBUCK];
    __shared__ unsigned int reorder[L1_CHUNK];
    int t = threadIdx.x;
    int e0 = blockIdx.x * L1_CHUNK;
    int cnt_here = min(etot - e0, L1_CHUNK);

    hist[t] = 0;
    __syncthreads();

    unsigned int myv[L1_PER_THREAD];
    #pragma unroll
    for (int j = 0; j < L1_PER_THREAD; ++j) {
        int e = e0 + j * L1_THREADS + t;
        if (e < etot) {
            int s, d;
            if (e < ne) { s = row[e]; d = colv[e]; } else { s = d = e - ne; }
            myv[j] = (unsigned int)s | ((unsigned int)d << 16);
            atomicAdd(&hist[d >> 7], 1u);
        } else myv[j] = 0xffffffffu;
    }
    __syncthreads();

    sa[t] = hist[t];
    __syncthreads();
    unsigned int* pin = sa;
    unsigned int* pout = sb;
    #pragma unroll
    for (int off = 1; off < MAXBUCK; off <<= 1) {
        pout[t] = pin[t] + ((t >= off) ? pin[t - off] : 0);
        __syncthreads();
        unsigned int* tmp = pin; pin = pout; pout = tmp;
    }
    unsigned int ex = pin[t] - hist[t];
    lbase[t] = ex;
    lcur[t]  = ex;
    if (t < nbuck && hist[t] > 0)
        runb[t] = (unsigned int)atomicAdd(&bucket_cursor[t], (int)hist[t]);
    __syncthreads();

    #pragma unroll
    for (int j = 0; j < L1_PER_THREAD; ++j) {
        unsigned int v = myv[j];
        if (v != 0xffffffffu) {
            unsigned int p = atomicAdd(&lcur[v >> 23], 1u);
            reorder[p] = v;
        }
    }
    __syncthreads();

    for (int i = t; i < cnt_here; i += L1_THREADS) {
        unsigned int v = reorder[i];
        unsigned int b = v >> 23;
        buck_arr[(size_t)b * CAP + runb[b] + ((unsigned int)i - lbase[b])] = v;
    }
}

__global__ __launch_bounds__(256) void k_fine(const unsigned int* __restrict__ buck_arr,
                                              const int* __restrict__ bucket_cursor,
                                              int* __restrict__ starts,
                                              int* __restrict__ ends,
                                              float* __restrict__ dinv,
                                              unsigned short* __restrict__ src16,
                                              int n) {
    int b = blockIdx.x;
    int base = b * CAP;
    int m = min(bucket_cursor[b], CAP);
    int node0 = b << 7;
    int nn = min(128, n - node0);
    __shared__ unsigned int cnt[128];
    __shared__ unsigned int lsc[256];
    __shared__ unsigned int lcur[128];
    __shared__ unsigned short srcbuf[CAP];
    int t = threadIdx.x;
    if (t < 128) cnt[t] = 0;
    __syncthreads();
    for (int i = t; i < m; i += 256)
        atomicAdd(&cnt[(buck_arr[base + i] >> 16) - node0], 1u);
    __syncthreads();
    unsigned int v0 = (t < 128) ? cnt[t] : 0;
    lsc[t] = v0;
    __syncthreads();
    #pragma unroll
    for (int off = 1; off < 128; off <<= 1) {
        unsigned int add = (t >= off) ? lsc[t - off] : 0;
        __syncthreads();
        lsc[t] += add;
        __syncthreads();
    }
    if (t < 128) {
        unsigned int ex = lsc[t] - v0;
        lcur[t] = ex;
        if (t < nn) {
            starts[node0 + t] = base + (int)ex;
            ends[node0 + t]   = base + (int)(ex + v0);
            dinv[node0 + t]   = rsqrtf((float)v0);
        }
    }
    __syncthreads();
    for (int i = t; i < m; i += 256) {
        unsigned int v = buck_arr[base + i];
        unsigned int p = atomicAdd(&lcur[(v >> 16) - node0], 1u);
        srcbuf[p] = (unsigned short)(v & 0xffffu);
    }
    __syncthreads();
    for (int i = t; i < m; i += 256)
        src16[base + i] = srcbuf[i];
}

__global__ __launch_bounds__(256) void k_gemm_mfma(const float* __restrict__ Af,
                                                   const unsigned short* __restrict__ Ab,
                                                   const unsigned short* __restrict__ Whi,
                                                   const unsigned short* __restrict__ Wlo,
                                                   const float* __restrict__ dinv,
                                                   unsigned char* __restrict__ Out,
                                                   int M) {
    __shared__ unsigned short As[64 * 136];
    int tid = threadIdx.x;
    int row0 = blockIdx.x * 64;

    if (Af) {
        for (int c = tid; c < 1024; c += 256) {
            int r = c >> 4, off = c & 15;
            int gr = min(row0 + r, M - 1);
            const float4* p = (const float4*)(Af + (size_t)gr * NF) + off * 2;
            float4 v0 = p[0], v1 = p[1];
            uint4 pk;
            pk.x = pack_bf16_rne(v0.x, v0.y);
            pk.y = pack_bf16_rne(v0.z, v0.w);
            pk.z = pack_bf16_rne(v1.x, v1.y);
            pk.w = pack_bf16_rne(v1.z, v1.w);
            *(uint4*)(&As[r * 136 + off * 8]) = pk;
        }
    } else {
        for (int c = tid; c < 1024; c += 256) {
            int r = c >> 4, off = c & 15;
            int gr = min(row0 + r, M - 1);
            *(uint4*)(&As[r * 136 + off * 8]) = ((const uint4*)(Ab + (size_t)gr * NF))[off];
        }
    }
    __syncthreads();

    int wave = tid >> 6, l = tid & 63;
    int q = l >> 4, c16 = l & 15;
    int wrow0 = wave * 16;

    floatx4 acc[8];
    #pragma unroll
    for (int t = 0; t < 8; ++t) acc[t] = (floatx4){0.f, 0.f, 0.f, 0.f};

    #pragma unroll
    for (int s = 0; s < 4; ++s) {
        short8 a = *(const short8*)(&As[(wrow0 + c16) * 136 + s * 32 + q * 8]);
        #pragma unroll
        for (int t = 0; t < 8; ++t) {
            short8 bh = *(const short8*)(Whi + ((size_t)((s * 8 + t) * 64 + l) * 8));
            acc[t] = __builtin_amdgcn_mfma_f32_16x16x32_bf16(a, bh, acc[t], 0, 0, 0);
            short8 bl = *(const short8*)(Wlo + ((size_t)((s * 8 + t) * 64 + l) * 8));
            acc[t] = __builtin_amdgcn_mfma_f32_16x16x32_bf16(a, bl, acc[t], 0, 0, 0);
        }
    }

    float ds[4];
    #pragma unroll
    for (int i = 0; i < 4; ++i) {
        int gr = row0 + wrow0 + q * 4 + i;
        ds[i] = (gr < M) ? dinv[gr] : 0.f;
    }
    #pragma unroll
    for (int t = 0; t < 8; ++t) {
        #pragma unroll
        for (int i = 0; i < 4; ++i) {
            int gr = row0 + wrow0 + q * 4 + i;
            if (gr < M) {
                float v = acc[t][i] * ds[i];
                unsigned int pk = __builtin_amdgcn_cvt_pk_fp8_f32(v, v, 0, false);
                Out[(size_t)gr * NF + t * 16 + c16] = (unsigned char)(pk & 0xffu);
            }
        }
    }
}

__global__ __launch_bounds__(256) void k_agg_fp8(const unsigned char* __restrict__ hs8,
                                                 const int* __restrict__ starts,
                                                 const int* __restrict__ ends,
                                                 const unsigned short* __restrict__ src16,
                                                 const float* __restrict__ dinv,
                                                 const float* __restrict__ bias,
                                                 unsigned short* __restrict__ out,
                                                 int n, int do_relu) {
    int wave = threadIdx.x >> 6;
    int lane = threadIdx.x & 63;
    int node = blockIdx.x * 4 + wave;
    if (node >= n) return;
    int g = lane >> 4;
    int f = lane & 15;
    int start = starts[node], end = ends[node];

    const uint2* h2 = (const uint2*)hs8;
    float acc[8];
    #pragma unroll
    for (int j = 0; j < 8; ++j) acc[j] = 0.f;

    for (int base = start; base < end; base += 32) {
        int   sidx[8];
        float msk[8];
        #pragma unroll
        for (int j = 0; j < 8; ++j) {
            int e = base + g + 4 * j;
            bool v = e < end;
            sidx[j] = (int)src16[v ? e : start];
            msk[j]  = v ? 1.f : 0.f;
        }
        uint2 rr[8];
        #pragma unroll
        for (int j = 0; j < 8; ++j)
            rr[j] = h2[(size_t)sidx[j] * 16 + f];
        #pragma unroll
        for (int j = 0; j < 8; ++j) {
            float m = msk[j];
            floatx2 p0 = __builtin_amdgcn_cvt_pk_f32_fp8(rr[j].x, false);
            floatx2 p1 = __builtin_amdgcn_cvt_pk_f32_fp8(rr[j].x, true);
            floatx2 p2 = __builtin_amdgcn_cvt_pk_f32_fp8(rr[j].y, false);
            floatx2 p3 = __builtin_amdgcn_cvt_pk_f32_fp8(rr[j].y, true);
            acc[0] = fmaf(m, p0.x, acc[0]);
            acc[1] = fmaf(m, p0.y, acc[1]);
            acc[2] = fmaf(m, p1.x, acc[2]);
            acc[3] = fmaf(m, p1.y, acc[3]);
            acc[4] = fmaf(m, p2.x, acc[4]);
            acc[5] = fmaf(m, p2.y, acc[5]);
            acc[6] = fmaf(m, p3.x, acc[6]);
            acc[7] = fmaf(m, p3.y, acc[7]);
        }
    }

    #pragma unroll
    for (int j = 0; j < 8; ++j) {
        acc[j] += __shfl_xor(acc[j], 16);
        acc[j] += __shfl_xor(acc[j], 32);
    }

    if (g == 0) {
        float dd = dinv[node];
        float4 b0 = ((const float4*)bias)[2 * f];
        float4 b1 = ((const float4*)bias)[2 * f + 1];
        float r[8];
        r[0] = fmaf(dd, acc[0], b0.x); r[1] = fmaf(dd, acc[1], b0.y);
        r[2] = fmaf(dd, acc[2], b0.z); r[3] = fmaf(dd, acc[3], b0.w);
        r[4] = fmaf(dd, acc[4], b1.x); r[5] = fmaf(dd, acc[5], b1.y);
        r[6] = fmaf(dd, acc[6], b1.z); r[7] = fmaf(dd, acc[7], b1.w);
        if (do_relu) {
            #pragma unroll
            for (int j = 0; j < 8; ++j) r[j] = fmaxf(r[j], 0.f);
        }
        uint4 pk;
        pk.x = pack_bf16_rne(r[0], r[1]);
        pk.y = pack_bf16_rne(r[2], r[3]);
        pk.z = pack_bf16_rne(r[4], r[5]);
        pk.w = pack_bf16_rne(r[6], r[7]);
        ((uint4*)out)[(size_t)node * 16 + f] = pk;
    }
}

__global__ __launch_bounds__(128) void k_pool_partial(const unsigned short* __restrict__ h,
                                                      const int* __restrict__ batch,
                                                      float* __restrict__ pooled_part,
                                                      int n) {
    int b = blockIdx.x;
    int g = b / PPG;
    int j = b % PPG;
    int t = threadIdx.x;

    int lo = 0, hi = n;
    while (lo < hi) { int mid = (lo + hi) >> 1; if (batch[mid] < g) lo = mid + 1; else hi = mid; }
    int s = lo;
    lo = s; hi = n;
    while (lo < hi) { int mid = (lo + hi) >> 1; if (batch[mid] < g + 1) lo = mid + 1; else hi = mid; }
    int e = lo;

    int len = e - s;
    int chunk = (len + PPG - 1) / PPG;
    int i0 = s + j * chunk;
    int i1 = min(e, i0 + chunk);

    float acc = 0.f;
    for (int i = i0; i < i1; ++i)
        acc += __uint_as_float((unsigned int)h[(size_t)i * NF + t] << 16);
    pooled_part[(size_t)b * NF + t] = acc;
}

__global__ __launch_bounds__(1024) void k_head(const float* __restrict__ pooled_part,
                                               const int* __restrict__ batch,
                                               const float* __restrict__ linW,
                                               const float* __restrict__ linb,
                                               float* __restrict__ out,
                                               int n, int n_graphs) {
    __shared__ float ph[64 * NF];
    int t = threadIdx.x;
    for (int i = t; i < n_graphs * NF; i += 1024) {
        int g = i >> 7, f = i & 127;
        float s = 0.f;
        #pragma unroll
        for (int j = 0; j < PPG; ++j)
            s += pooled_part[(size_t)(g * PPG + j) * NF + f];
        ph[i] = s;
    }
    __syncthreads();

    int g = t >> 4;
    int c = t & 15;

    int lo = 0, hi = n;
    while (lo < hi) { int mid = (lo + hi) >> 1; if (batch[mid] < g) lo = mid + 1; else hi = mid; }
    int start = lo;
    lo = start; hi = n;
    while (lo < hi) { int mid = (lo + hi) >> 1; if (batch[mid] < g + 1) lo = mid + 1; else hi = mid; }
    float inv_cnt = 1.f / fmaxf((float)(lo - start), 1.f);

    float acc = linb[c];
    for (int k = 0; k < NF; ++k)
        acc += ph[g * NF + k] * inv_cnt * linW[k * 16 + c];

    float m = acc;
    #pragma unroll
    for (int s2 = 8; s2 >= 1; s2 >>= 1) m = fmaxf(m, __shfl_xor(m, s2, 16));
    float e = expf(acc - m);
    float ssum = e;
    #pragma unroll
    for (int s2 = 8; s2 >= 1; s2 >>= 1) ssum += __shfl_xor(ssum, s2, 16);
    out[g * 16 + c] = e / ssum;
}

// ---------------- host ----------------

extern "C" void kernel_launch(void* const* d_in, const int* in_sizes, int n_in,
                              void* d_out, int out_size, void* d_ws, size_t ws_size,
                              hipStream_t stream) {
    const float* x    = (const float*)d_in[0];
    const int*   edge = (const int*)d_in[1];
    const int*   batch= (const int*)d_in[2];
    const float* W0   = (const float*)d_in[3];
    const float* b0   = (const float*)d_in[4];
    const float* W1   = (const float*)d_in[5];
    const float* b1   = (const float*)d_in[6];
    const float* W2   = (const float*)d_in[7];
    const float* b2   = (const float*)d_in[8];
    const float* linW = (const float*)d_in[9];
    const float* linb = (const float*)d_in[10];

    int n  = in_sizes[0] / NF;       // 50000
    int ne = in_sizes[1] / 2;        // 800000
    int n_graphs = out_size / 16;    // 64
    const int* row  = edge;
    const int* colv = edge + ne;
    int etot = ne + n;
    int nbuck = (n + 127) >> 7;      // 391

    char* pws = (char*)d_ws;
    auto alloc = [&](size_t bytes) { char* r = pws; pws += (bytes + 255) & ~(size_t)255; return r; };
    int*   bucket_cursor = (int*)alloc((size_t)(MAXBUCK + 1) * 4);
    unsigned int* buck_arr = (unsigned int*)alloc((size_t)MAXBUCK * CAP * 4);
    unsigned short* src16  = (unsigned short*)alloc((size_t)MAXBUCK * CAP * 2);
    int*   starts  = (int*)  alloc((size_t)n * 4);
    int*   ends    = (int*)  alloc((size_t)n * 4);
    float* dinvp   = (float*)alloc((size_t)n * 4);
    unsigned char*  gbuf8 = (unsigned char*) alloc((size_t)n * NF);
    unsigned short* abuf  = (unsigned short*)alloc((size_t)n * NF * 2);
    float* pooled_part = (float*)alloc((size_t)n_graphs * PPG * NF * 4);
    unsigned short* whi = (unsigned short*)alloc((size_t)3 * NF * NF * 2);
    unsigned short* wlo = (unsigned short*)alloc((size_t)3 * NF * NF * 2);

    KP p;
    p.x = x; p.row = row; p.colv = colv; p.batch = batch;
    p.W0 = W0; p.b0 = b0; p.W1 = W1; p.b1 = b1; p.W2 = W2; p.b2 = b2;
    p.linW = linW; p.linb = linb;
    p.bucket_cursor = bucket_cursor; p.buck_arr = buck_arr; p.src16 = src16;
    p.starts = starts; p.ends = ends; p.dinv = dinvp;
    p.gbuf8 = gbuf8; p.abuf = abuf; p.pooled_part = pooled_part;
    p.whi = whi; p.wlo = wlo;
    p.out = (float*)d_out;
    p.n = n; p.ne = ne; p.etot = etot; p.nbuck = nbuck; p.n_graphs = n_graphs;

    int per_cu = 0;
    hipError_t oe = hipOccupancyMaxActiveBlocksPerMultiprocessor(
        &per_cu, reinterpret_cast<const void*>(k_all), 256, 0);
    if (oe != hipSuccess || per_cu < 1) per_cu = 2;
    if (per_cu > 8) per_cu = 8;
    int grid = per_cu * 256;   // MI355X: 256 CUs; co-residency guaranteed by occupancy query

    void* kargs[] = { (void*)&p };
    hipError_t err = hipLaunchCooperativeKernel(reinterpret_cast<const void*>(k_all),
                                                dim3(grid), dim3(256), kargs, 0, stream);
    if (err != hipSuccess) {
        // fallback: proven 11-kernel pipeline (R9)
        k_repack_w3<<<24, 256, 0, stream>>>(W0, W1, W2, whi, wlo, bucket_cursor);
        k_bucket_scatter<<<(etot + L1_CHUNK - 1) / L1_CHUNK, L1_THREADS, 0, stream>>>(
            row, colv, bucket_cursor, buck_arr, ne, etot, nbuck);
        k_fine<<<nbuck, 256, 0, stream>>>(buck_arr, bucket_cursor, starts, ends, dinvp, src16, n);

        int gemm_blocks = (n + 63) / 64;
        int agg_blocks  = (n + 3) / 4;
        const size_t WSLAB = (size_t)NF * NF;

        k_gemm_mfma<<<gemm_blocks, 256, 0, stream>>>(x, nullptr, whi, wlo, dinvp, gbuf8, n);
        k_agg_fp8  <<<agg_blocks, 256, 0, stream>>>(gbuf8, starts, ends, src16, dinvp, b0, abuf, n, 1);
        k_gemm_mfma<<<gemm_blocks, 256, 0, stream>>>(nullptr, abuf, whi + WSLAB, wlo + WSLAB, dinvp, gbuf8, n);
        k_agg_fp8  <<<agg_blocks, 256, 0, stream>>>(gbuf8, starts, ends, src16, dinvp, b1, abuf, n, 1);
        k_gemm_mfma<<<gemm_blocks, 256, 0, stream>>>(nullptr, abuf, whi + 2 * WSLAB, wlo + 2 * WSLAB, dinvp, gbuf8, n);
        k_agg_fp8  <<<agg_blocks, 256, 0, stream>>>(gbuf8, starts, ends, src16, dinvp, b2, abuf, n, 0);

        k_pool_partial<<<n_graphs * PPG, 128, 0, stream>>>(abuf, batch, pooled_part, n);
        k_head<<<1, 1024, 0, stream>>>(pooled_part, batch, linW, linb, (float*)d_out, n, n_graphs);
    }
}

// Round 2
// 277.180 us; speedup vs baseline: 5.5859x; 5.5859x over previous
//
#include <hip/hip_runtime.h>

// GCN: 3x (GEMM 128x128 + normalized scatter-sum) + mean-pool + linear + softmax.
// R1: two-stage pool. R2: parallel scan. R3: bf16 + split-W MFMA GEMM.
// R4: agg multi-edge-in-flight; h pre-scaled by dinv (edges carry only src idx).
// R5: CSR via two-level bucket sort. R6 FAILED (fusion cut gather parallelism).
// R7: agg 16 edges in flight; slab CSR. R8: 32 edges in flight; atomic/memset-free pool.
// R9: gbuf fp8 e4m3 gather payload (292 us).
// R10 FAILED (single cooperative kernel, 10 grid.sync: device-scope sync flushed
//     per-XCD L2s -> 505 MB HBM traffic/dispatch @ 210 GB/s = 2.4 ms; gather
//     parallelism also cut. Kernel-boundary caching is what makes R9 fast.)
// R11: revert to R9 structure + (a) GEMM 128-row blocks, 32 rows/wave: halves
//      W-fragment load issue & L2 W traffic (2:1 MFMA:load, bitwise-same acc order);
//      (b) pool uint4 loads (16B/lane vs 2B/lane scalar bf16);
//      (c) scatter chunk 8192->4096 (104 -> 208 blocks, CU occupancy 2x).
// Assumes n <= 65536 (src packed u16), n <= 512*128, bucket load < CAP (8.5σ).

#define NF 128
#define MAXBUCK 512
#define CAP 2560           // slab capacity per bucket (mean 2176, sigma ~45)
#define L1_CHUNK 4096
#define L1_THREADS 512
#define L1_PER_THREAD 8    // L1_CHUNK / L1_THREADS
#define PPG 8              // pool partials per graph

typedef __attribute__((ext_vector_type(8))) short short8;
typedef __attribute__((ext_vector_type(4))) float floatx4;
typedef __attribute__((ext_vector_type(2))) float floatx2;

__device__ __forceinline__ unsigned int bf16_rne(float x) {
    unsigned int u = __float_as_uint(x);
    return (u + 0x7fffu + ((u >> 16) & 1u)) >> 16;
}
__device__ __forceinline__ unsigned int pack_bf16_rne(float x, float y) {
    return bf16_rne(x) | (bf16_rne(y) << 16);
}
__device__ __forceinline__ float bf16u_to_f32(unsigned int u) {
    return __uint_as_float(u << 16);
}

// ---- repack all 3 W (fp32 [k][n]) into B-fragment-major bf16 hi/lo.
// Block 0 also zeroes the (slab-relative) bucket cursors — runs before scatter. ----
__global__ __launch_bounds__(256) void k_repack_w3(const float* __restrict__ W0,
                                                   const float* __restrict__ W1,
                                                   const float* __restrict__ W2,
                                                   unsigned short* __restrict__ whi,
                                                   unsigned short* __restrict__ wlo,
                                                   int* __restrict__ bucket_cursor) {
    if (blockIdx.x == 0) {
        for (int i = threadIdx.x; i <= MAXBUCK; i += 256) bucket_cursor[i] = 0;
    }
    int wsel = blockIdx.x >> 3;
    const float* W = (wsel == 0) ? W0 : (wsel == 1) ? W1 : W2;
    int idx = (blockIdx.x & 7) * 256 + threadIdx.x;  // 0..2047
    int slab = wsel * NF * NF;
    int l = idx & 63;
    int t = (idx >> 6) & 7;
    int s = idx >> 9;
    int kbase = s * 32 + (l >> 4) * 8;
    int nn = t * 16 + (l & 15);
    #pragma unroll
    for (int j = 0; j < 8; ++j) {
        float w = W[(kbase + j) * NF + nn];
        unsigned int h = bf16_rne(w);
        float hf = __uint_as_float(h << 16);
        unsigned int lo = bf16_rne(w - hf);
        whi[slab + idx * 8 + j] = (unsigned short)h;
        wlo[slab + idx * 8 + j] = (unsigned short)lo;
    }
}

// ---- CSR A: bucket-grouped scatter into fixed slabs via LDS reorder ----
__global__ __launch_bounds__(L1_THREADS) void k_bucket_scatter(
        const int* __restrict__ row, const int* __restrict__ colv,
        int* __restrict__ bucket_cursor, unsigned int* __restrict__ buck_arr,
        int ne, int etot, int nbuck) {
    __shared__ unsigned int hist[MAXBUCK];
    __shared__ unsigned int lbase[MAXBUCK];
    __shared__ unsigned int lcur[MAXBUCK];
    __shared__ unsigned int runb[MAXBUCK];
    __shared__ unsigned int sa[MAXBUCK], sb[MAXBUCK];
    __shared__ unsigned int reorder[L1_CHUNK];
    int t = threadIdx.x;
    int e0 = blockIdx.x * L1_CHUNK;
    int cnt_here = min(etot - e0, L1_CHUNK);

    hist[t] = 0;
    __syncthreads();

    unsigned int myv[L1_PER_THREAD];
    #pragma unroll
    for (int j = 0; j < L1_PER_THREAD; ++j) {
        int e = e0 + j * L1_THREADS + t;
        if (e < etot) {
            int s, d;
            if (e < ne) { s = row[e]; d = colv[e]; } else { s = d = e - ne; }
            myv[j] = (unsigned int)s | ((unsigned int)d << 16);
            atomicAdd(&hist[d >> 7], 1u);
        } else myv[j] = 0xffffffffu;
    }
    __syncthreads();

    sa[t] = hist[t];
    __syncthreads();
    unsigned int* pin = sa;
    unsigned int* pout = sb;
    #pragma unroll
    for (int off = 1; off < MAXBUCK; off <<= 1) {
        pout[t] = pin[t] + ((t >= off) ? pin[t - off] : 0);
        __syncthreads();
        unsigned int* tmp = pin; pin = pout; pout = tmp;
    }
    unsigned int ex = pin[t] - hist[t];
    lbase[t] = ex;
    lcur[t]  = ex;
    if (t < nbuck && hist[t] > 0)
        runb[t] = (unsigned int)atomicAdd(&bucket_cursor[t], (int)hist[t]);
    __syncthreads();

    #pragma unroll
    for (int j = 0; j < L1_PER_THREAD; ++j) {
        unsigned int v = myv[j];
        if (v != 0xffffffffu) {
            unsigned int p = atomicAdd(&lcur[v >> 23], 1u);
            reorder[p] = v;
        }
    }
    __syncthreads();

    for (int i = t; i < cnt_here; i += L1_THREADS) {
        unsigned int v = reorder[i];
        unsigned int b = v >> 23;
        buck_arr[(size_t)b * CAP + runb[b] + ((unsigned int)i - lbase[b])] = v;
    }
}

// ---- CSR B: per-bucket fine sort; emits src16 (slab-local), starts/ends/dinv ----
__global__ __launch_bounds__(256) void k_fine(const unsigned int* __restrict__ buck_arr,
                                              const int* __restrict__ bucket_cursor,
                                              int* __restrict__ starts,
                                              int* __restrict__ ends,
                                              float* __restrict__ dinv,
                                              unsigned short* __restrict__ src16,
                                              int n) {
    int b = blockIdx.x;
    int base = b * CAP;
    int m = min(bucket_cursor[b], CAP);
    int node0 = b << 7;
    int nn = min(128, n - node0);
    __shared__ unsigned int cnt[128];
    __shared__ unsigned int lsc[256];
    __shared__ unsigned int lcur[128];
    __shared__ unsigned short srcbuf[CAP];
    int t = threadIdx.x;
    if (t < 128) cnt[t] = 0;
    __syncthreads();
    for (int i = t; i < m; i += 256)
        atomicAdd(&cnt[(buck_arr[base + i] >> 16) - node0], 1u);
    __syncthreads();
    unsigned int v0 = (t < 128) ? cnt[t] : 0;
    lsc[t] = v0;
    __syncthreads();
    #pragma unroll
    for (int off = 1; off < 128; off <<= 1) {
        unsigned int add = (t >= off) ? lsc[t - off] : 0;
        __syncthreads();
        lsc[t] += add;
        __syncthreads();
    }
    if (t < 128) {
        unsigned int ex = lsc[t] - v0;
        lcur[t] = ex;
        if (t < nn) {
            starts[node0 + t] = base + (int)ex;
            ends[node0 + t]   = base + (int)(ex + v0);
            dinv[node0 + t]   = rsqrtf((float)v0);   // deg >= 1 (self-loop)
        }
    }
    __syncthreads();
    for (int i = t; i < m; i += 256) {
        unsigned int v = buck_arr[base + i];
        unsigned int p = atomicAdd(&lcur[(v >> 16) - node0], 1u);
        srcbuf[p] = (unsigned short)(v & 0xffffu);
    }
    __syncthreads();
    for (int i = t; i < m; i += 256)
        src16[base + i] = srcbuf[i];
}

// ---- GEMM: Out[M,128](fp8 e4m3, pre-scaled by dinv[row]) = A @ (Whi+Wlo)
// R11: 128 rows/block, 32 rows/wave (2 row-tiles) per W-fragment load:
// 2:1 MFMA:global-load, halves W issue + L2 W traffic vs 64-row blocks. ----
__global__ __launch_bounds__(256) void k_gemm_mfma(const float* __restrict__ Af,
                                                   const unsigned short* __restrict__ Ab,
                                                   const unsigned short* __restrict__ Whi,
                                                   const unsigned short* __restrict__ Wlo,
                                                   const float* __restrict__ dinv,
                                                   unsigned char* __restrict__ Out,
                                                   int M) {
    __shared__ unsigned short As[128 * 136];   // 34 KB
    int tid = threadIdx.x;
    int row0 = blockIdx.x * 128;

    if (Af) {
        for (int c = tid; c < 2048; c += 256) {
            int r = c >> 4, off = c & 15;
            int gr = min(row0 + r, M - 1);
            const float4* p = (const float4*)(Af + (size_t)gr * NF) + off * 2;
            float4 v0 = p[0], v1 = p[1];
            uint4 pk;
            pk.x = pack_bf16_rne(v0.x, v0.y);
            pk.y = pack_bf16_rne(v0.z, v0.w);
            pk.z = pack_bf16_rne(v1.x, v1.y);
            pk.w = pack_bf16_rne(v1.z, v1.w);
            *(uint4*)(&As[r * 136 + off * 8]) = pk;
        }
    } else {
        for (int c = tid; c < 2048; c += 256) {
            int r = c >> 4, off = c & 15;
            int gr = min(row0 + r, M - 1);
            *(uint4*)(&As[r * 136 + off * 8]) = ((const uint4*)(Ab + (size_t)gr * NF))[off];
        }
    }
    __syncthreads();

    int wave = tid >> 6, l = tid & 63;
    int q = l >> 4, c16 = l & 15;
    int wrow0 = wave * 16;

    floatx4 acc[2][8];
    #pragma unroll
    for (int h = 0; h < 2; ++h)
        #pragma unroll
        for (int t = 0; t < 8; ++t) acc[h][t] = (floatx4){0.f, 0.f, 0.f, 0.f};

    #pragma unroll
    for (int s = 0; s < 4; ++s) {
        short8 a0 = *(const short8*)(&As[(wrow0 + c16) * 136 + s * 32 + q * 8]);
        short8 a1 = *(const short8*)(&As[(64 + wrow0 + c16) * 136 + s * 32 + q * 8]);
        #pragma unroll
        for (int t = 0; t < 8; ++t) {
            short8 bh = *(const short8*)(Whi + ((size_t)((s * 8 + t) * 64 + l) * 8));
            short8 bl = *(const short8*)(Wlo + ((size_t)((s * 8 + t) * 64 + l) * 8));
            acc[0][t] = __builtin_amdgcn_mfma_f32_16x16x32_bf16(a0, bh, acc[0][t], 0, 0, 0);
            acc[0][t] = __builtin_amdgcn_mfma_f32_16x16x32_bf16(a0, bl, acc[0][t], 0, 0, 0);
            acc[1][t] = __builtin_amdgcn_mfma_f32_16x16x32_bf16(a1, bh, acc[1][t], 0, 0, 0);
            acc[1][t] = __builtin_amdgcn_mfma_f32_16x16x32_bf16(a1, bl, acc[1][t], 0, 0, 0);
        }
    }

    #pragma unroll
    for (int h = 0; h < 2; ++h) {
        float ds[4];
        #pragma unroll
        for (int i = 0; i < 4; ++i) {
            int gr = row0 + h * 64 + wrow0 + q * 4 + i;
            ds[i] = (gr < M) ? dinv[gr] : 0.f;
        }
        #pragma unroll
        for (int t = 0; t < 8; ++t) {
            #pragma unroll
            for (int i = 0; i < 4; ++i) {
                int gr = row0 + h * 64 + wrow0 + q * 4 + i;
                if (gr < M) {
                    float v = acc[h][t][i] * ds[i];
                    unsigned int pk = __builtin_amdgcn_cvt_pk_fp8_f32(v, v, 0, false);
                    Out[(size_t)gr * NF + t * 16 + c16] = (unsigned char)(pk & 0xffu);
                }
            }
        }
    }
}

// ---- out[i] = relu?( dinv[i] * sum_e h8[src_e] + b ), h8 fp8 pre-scaled.
// One wave/node; lane = (slot g=l>>4, feat f=l&15); uint2 (8 fp8 feats)/lane;
// 4 slots x unroll 8 = 32 edges in flight. Tail via 0/1 fma mask. ----
__global__ __launch_bounds__(256) void k_agg_fp8(const unsigned char* __restrict__ hs8,
                                                 const int* __restrict__ starts,
                                                 const int* __restrict__ ends,
                                                 const unsigned short* __restrict__ src16,
                                                 const float* __restrict__ dinv,
                                                 const float* __restrict__ bias,
                                                 unsigned short* __restrict__ out,
                                                 int n, int do_relu) {
    int wave = threadIdx.x >> 6;
    int lane = threadIdx.x & 63;
    int node = blockIdx.x * 4 + wave;
    if (node >= n) return;
    int g = lane >> 4;
    int f = lane & 15;
    int start = starts[node], end = ends[node];

    const uint2* h2 = (const uint2*)hs8;   // 16 uint2 per 128-feat fp8 row
    float acc[8];
    #pragma unroll
    for (int j = 0; j < 8; ++j) acc[j] = 0.f;

    for (int base = start; base < end; base += 32) {
        int   sidx[8];
        float msk[8];
        #pragma unroll
        for (int j = 0; j < 8; ++j) {
            int e = base + g + 4 * j;
            bool v = e < end;
            sidx[j] = (int)src16[v ? e : start];  // masked slots reload a VALID row (no NaN decode)
            msk[j]  = v ? 1.f : 0.f;
        }
        uint2 rr[8];
        #pragma unroll
        for (int j = 0; j < 8; ++j)
            rr[j] = h2[(size_t)sidx[j] * 16 + f];
        #pragma unroll
        for (int j = 0; j < 8; ++j) {
            float m = msk[j];
            floatx2 p0 = __builtin_amdgcn_cvt_pk_f32_fp8(rr[j].x, false);
            floatx2 p1 = __builtin_amdgcn_cvt_pk_f32_fp8(rr[j].x, true);
            floatx2 p2 = __builtin_amdgcn_cvt_pk_f32_fp8(rr[j].y, false);
            floatx2 p3 = __builtin_amdgcn_cvt_pk_f32_fp8(rr[j].y, true);
            acc[0] = fmaf(m, p0.x, acc[0]);
            acc[1] = fmaf(m, p0.y, acc[1]);
            acc[2] = fmaf(m, p1.x, acc[2]);
            acc[3] = fmaf(m, p1.y, acc[3]);
            acc[4] = fmaf(m, p2.x, acc[4]);
            acc[5] = fmaf(m, p2.y, acc[5]);
            acc[6] = fmaf(m, p3.x, acc[6]);
            acc[7] = fmaf(m, p3.y, acc[7]);
        }
    }

    // fold the 4 edge slots (lanes 16 apart hold the same feat group)
    #pragma unroll
    for (int j = 0; j < 8; ++j) {
        acc[j] += __shfl_xor(acc[j], 16);
        acc[j] += __shfl_xor(acc[j], 32);
    }

    if (g == 0) {
        float dd = dinv[node];
        float4 b0 = ((const float4*)bias)[2 * f];
        float4 b1 = ((const float4*)bias)[2 * f + 1];
        float r[8];
        r[0] = fmaf(dd, acc[0], b0.x); r[1] = fmaf(dd, acc[1], b0.y);
        r[2] = fmaf(dd, acc[2], b0.z); r[3] = fmaf(dd, acc[3], b0.w);
        r[4] = fmaf(dd, acc[4], b1.x); r[5] = fmaf(dd, acc[5], b1.y);
        r[6] = fmaf(dd, acc[6], b1.z); r[7] = fmaf(dd, acc[7], b1.w);
        if (do_relu) {
            #pragma unroll
            for (int j = 0; j < 8; ++j) r[j] = fmaxf(r[j], 0.f);
        }
        uint4 pk;
        pk.x = pack_bf16_rne(r[0], r[1]);
        pk.y = pack_bf16_rne(r[2], r[3]);
        pk.z = pack_bf16_rne(r[4], r[5]);
        pk.w = pack_bf16_rne(r[6], r[7]);
        ((uint4*)out)[(size_t)node * 16 + f] = pk;
    }
}

// ---- pooling: deterministic partial slabs (no atomics, no memset).
// R11: uint4 loads (16B/lane), 8-row register tile + LDS fold. ----
__global__ __launch_bounds__(128) void k_pool_partial(const unsigned short* __restrict__ h,
                                                      const int* __restrict__ batch,
                                                      float* __restrict__ pooled_part,
                                                      int n) {
    __shared__ float red[8][NF];
    int b = blockIdx.x;
    int g = b / PPG;
    int j = b % PPG;
    int t = threadIdx.x;

    int lo = 0, hi = n;
    while (lo < hi) { int mid = (lo + hi) >> 1; if (batch[mid] < g) lo = mid + 1; else hi = mid; }
    int s = lo;
    lo = s; hi = n;
    while (lo < hi) { int mid = (lo + hi) >> 1; if (batch[mid] < g + 1) lo = mid + 1; else hi = mid; }
    int e = lo;

    int len = e - s;
    int chunk = (len + PPG - 1) / PPG;
    int i0 = s + j * chunk;
    int i1 = min(e, i0 + chunk);

    int r = t >> 4, f8 = t & 15;       // row-slot 0..7, feature-group 0..15
    float acc[8];
    #pragma unroll
    for (int k = 0; k < 8; ++k) acc[k] = 0.f;
    for (int i = i0 + r; i < i1; i += 8) {
        uint4 v = *(const uint4*)(&h[(size_t)i * NF + f8 * 8]);
        acc[0] += bf16u_to_f32(v.x & 0xffffu); acc[1] += bf16u_to_f32(v.x >> 16);
        acc[2] += bf16u_to_f32(v.y & 0xffffu); acc[3] += bf16u_to_f32(v.y >> 16);
        acc[4] += bf16u_to_f32(v.z & 0xffffu); acc[5] += bf16u_to_f32(v.z >> 16);
        acc[6] += bf16u_to_f32(v.w & 0xffffu); acc[7] += bf16u_to_f32(v.w >> 16);
    }
    #pragma unroll
    for (int k = 0; k < 8; ++k) red[r][f8 * 8 + k] = acc[k];
    __syncthreads();
    float ssum = 0.f;
    #pragma unroll
    for (int rr = 0; rr < 8; ++rr) ssum += red[rr][t];
    pooled_part[(size_t)b * NF + t] = ssum;
}

// ---- head: fold partials in LDS, counts + linear 128x16 + softmax ----
__global__ __launch_bounds__(1024) void k_head(const float* __restrict__ pooled_part,
                                               const int* __restrict__ batch,
                                               const float* __restrict__ linW,
                                               const float* __restrict__ linb,
                                               float* __restrict__ out,
                                               int n, int n_graphs) {
    __shared__ float ph[64 * NF];  // 32 KB
    int t = threadIdx.x;
    for (int i = t; i < n_graphs * NF; i += 1024) {
        int g = i >> 7, f = i & 127;
        float s = 0.f;
        #pragma unroll
        for (int j = 0; j < PPG; ++j)
            s += pooled_part[(size_t)(g * PPG + j) * NF + f];
        ph[i] = s;
    }
    __syncthreads();

    int g = t >> 4;
    int c = t & 15;

    int lo = 0, hi = n;
    while (lo < hi) { int mid = (lo + hi) >> 1; if (batch[mid] < g) lo = mid + 1; else hi = mid; }
    int start = lo;
    lo = start; hi = n;
    while (lo < hi) { int mid = (lo + hi) >> 1; if (batch[mid] < g + 1) lo = mid + 1; else hi = mid; }
    float inv_cnt = 1.f / fmaxf((float)(lo - start), 1.f);

    float acc = linb[c];
    for (int k = 0; k < NF; ++k)
        acc += ph[g * NF + k] * inv_cnt * linW[k * 16 + c];

    float m = acc;
    #pragma unroll
    for (int s2 = 8; s2 >= 1; s2 >>= 1) m = fmaxf(m, __shfl_xor(m, s2, 16));
    float e = expf(acc - m);
    float ssum = e;
    #pragma unroll
    for (int s2 = 8; s2 >= 1; s2 >>= 1) ssum += __shfl_xor(ssum, s2, 16);
    out[g * 16 + c] = e / ssum;
}

extern "C" void kernel_launch(void* const* d_in, const int* in_sizes, int n_in,
                              void* d_out, int out_size, void* d_ws, size_t ws_size,
                              hipStream_t stream) {
    const float* x    = (const float*)d_in[0];
    const int*   edge = (const int*)d_in[1];
    const int*   batch= (const int*)d_in[2];
    const float* W0   = (const float*)d_in[3];
    const float* b0   = (const float*)d_in[4];
    const float* W1   = (const float*)d_in[5];
    const float* b1   = (const float*)d_in[6];
    const float* W2   = (const float*)d_in[7];
    const float* b2   = (const float*)d_in[8];
    const float* linW = (const float*)d_in[9];
    const float* linb = (const float*)d_in[10];

    int n  = in_sizes[0] / NF;       // 50000
    int ne = in_sizes[1] / 2;        // 800000
    int n_graphs = out_size / 16;    // 64
    const int* row  = edge;
    const int* colv = edge + ne;
    int etot = ne + n;
    int nbuck = (n + 127) >> 7;      // 391

    char* p = (char*)d_ws;
    auto alloc = [&](size_t bytes) { char* r = p; p += (bytes + 255) & ~(size_t)255; return r; };
    int*   bucket_cursor = (int*)alloc((size_t)(MAXBUCK + 1) * 4);
    unsigned int* buck_arr = (unsigned int*)alloc((size_t)MAXBUCK * CAP * 4);
    unsigned short* src16  = (unsigned short*)alloc((size_t)MAXBUCK * CAP * 2);
    int*   starts  = (int*)  alloc((size_t)n * 4);
    int*   ends    = (int*)  alloc((size_t)n * 4);
    float* dinv    = (float*)alloc((size_t)n * 4);
    unsigned char*  gbuf8 = (unsigned char*) alloc((size_t)n * NF);      // fp8 gemm out
    unsigned short* abuf  = (unsigned short*)alloc((size_t)n * NF * 2);  // bf16 agg out
    float* pooled_part = (float*)alloc((size_t)n_graphs * PPG * NF * 4);
    unsigned short* whi = (unsigned short*)alloc((size_t)3 * NF * NF * 2);
    unsigned short* wlo = (unsigned short*)alloc((size_t)3 * NF * NF * 2);

    // repack first (block 0 also zeroes bucket cursors)
    k_repack_w3<<<24, 256, 0, stream>>>(W0, W1, W2, whi, wlo, bucket_cursor);

    // CSR build (slab buckets)
    k_bucket_scatter<<<(etot + L1_CHUNK - 1) / L1_CHUNK, L1_THREADS, 0, stream>>>(
        row, colv, bucket_cursor, buck_arr, ne, etot, nbuck);
    k_fine<<<nbuck, 256, 0, stream>>>(buck_arr, bucket_cursor, starts, ends, dinv, src16, n);

    int gemm_blocks = (n + 127) / 128;
    int agg_blocks  = (n + 3) / 4;
    const size_t WSLAB = (size_t)NF * NF;

    k_gemm_mfma<<<gemm_blocks, 256, 0, stream>>>(x, nullptr, whi, wlo, dinv, gbuf8, n);
    k_agg_fp8  <<<agg_blocks, 256, 0, stream>>>(gbuf8, starts, ends, src16, dinv, b0, abuf, n, 1);
    k_gemm_mfma<<<gemm_blocks, 256, 0, stream>>>(nullptr, abuf, whi + WSLAB, wlo + WSLAB, dinv, gbuf8, n);
    k_agg_fp8  <<<agg_blocks, 256, 0, stream>>>(gbuf8, starts, ends, src16, dinv, b1, abuf, n, 1);
    k_gemm_mfma<<<gemm_blocks, 256, 0, stream>>>(nullptr, abuf, whi + 2 * WSLAB, wlo + 2 * WSLAB, dinv, gbuf8, n);
    k_agg_fp8  <<<agg_blocks, 256, 0, stream>>>(gbuf8, starts, ends, src16, dinv, b2, abuf, n, 0);

    // pool (no atomics/memset) + head
    k_pool_partial<<<n_graphs * PPG, 128, 0, stream>>>(abuf, batch, pooled_part, n);
    k_head<<<1, 1024, 0, stream>>>(pooled_part, batch, linW, linb, (float*)d_out, n, n_graphs);
}